// Round 5
// baseline (485.046 us; speedup 1.0000x reference)
//
#include <hip/hip_runtime.h>
#include <math.h>

// Model_39676907887961: out = dropout(softmax(x1@x2^T / x3)) @ x1 + x2
// B=2 H=16 S=2048 D=128. Round 5: BK=32, double-buffered K/V LDS (one
// barrier per tile, DMA prefetch hidden under compute), xnor/perm/and
// dropout apply, coalesced prepack. Grid-capped 4 blocks/CU (37.9 KB LDS).
// Threefry2x32 key(42) partitionable (verified r1); no-max softmax (r3).

constexpr int Sc = 2048, Dc = 128;
constexpr int BK = 32, NT = Sc / BK;        // 64 k-tiles
constexpr int TILE_B = 8192;                // one K or V tile image: 512 uint4
constexpr int PS_OFF = 32768;               // after 2 double-buffers
constexpr int PS_STRIDE = 80;               // bytes per P row (16-aligned)

typedef short bf16x8 __attribute__((ext_vector_type(8)));
typedef float f32x4 __attribute__((ext_vector_type(4)));
union U8 { uint4 u; bf16x8 v; };

__device__ __forceinline__ unsigned rotl32(unsigned x, int r) {
  return (x << r) | (x >> (32 - r));
}

// JAX Threefry-2x32, 20 rounds, key = (0, 42) — verified partitionable path
__device__ __forceinline__ void tf2x32(unsigned x0, unsigned x1,
                                       unsigned &o0, unsigned &o1) {
  const unsigned ks0 = 0u, ks1 = 42u;
  const unsigned ks2 = 0x1BD11BDAu ^ 0u ^ 42u;
  x0 += ks0; x1 += ks1;
#define TFR(r) { x0 += x1; x1 = rotl32(x1, r); x1 ^= x0; }
  TFR(13) TFR(15) TFR(26) TFR(6)
  x0 += ks1; x1 += ks2 + 1u;
  TFR(17) TFR(29) TFR(16) TFR(24)
  x0 += ks2; x1 += ks0 + 2u;
  TFR(13) TFR(15) TFR(26) TFR(6)
  x0 += ks0; x1 += ks1 + 3u;
  TFR(17) TFR(29) TFR(16) TFR(24)
  x0 += ks1; x1 += ks2 + 4u;
  TFR(13) TFR(15) TFR(26) TFR(6)
  x0 += ks2; x1 += ks0 + 5u;
#undef TFR
  o0 = x0; o1 = x1;
}

// keep-mask: 0xFFFFFFFF iff MSB(o0^o1)==0 (uniform<0.5 => keep)
__device__ __forceinline__ unsigned keepmask(unsigned idx) {
  unsigned a, b; tf2x32(0u, idx, a, b);
  return (unsigned)(((int)~(a ^ b)) >> 31);
}

// pack two f32 -> bf16 pair (round-half-up via +0x8000, then v_perm)
__device__ __forceinline__ unsigned pk2rn(float a, float b) {
  return __builtin_amdgcn_perm(__float_as_uint(b) + 0x8000u,
                               __float_as_uint(a) + 0x8000u, 0x07060302u);
}

// halfword-combine two full-width masks: lo16 from ma, hi16 from mb
__device__ __forceinline__ unsigned hw2(unsigned ma, unsigned mb) {
  return __builtin_amdgcn_perm(mb, ma, 0x05040100u);
}

__device__ __forceinline__ void gload16(const void* g, void* l) {
  __builtin_amdgcn_global_load_lds(
      (const __attribute__((address_space(1))) void*)g,
      (__attribute__((address_space(3))) void*)l, 16, 0, 0);
}

// ---------------- pre-pass: fragment-linear bf16 K and V^T images -----------
// Per 32-key tile (tile = bh*64 + t):
//  K unit u = (mt*4+c)*64 + lane : K[mt*16+(lane&15)][c*32+(lane>>4)*8 .. +7]
//  V unit u = dt*64 + lane       : V[(lane>>4)*8+2p(+1)][dt*16+(lane&15)] pairs
__global__ __launch_bounds__(256)
void prepack(const float* __restrict__ x1, const float* __restrict__ x2,
             uint4* __restrict__ Kb, uint4* __restrict__ Vt) {
  __shared__ ushort Kl[32 * 136];
  __shared__ ushort Vl[32 * 136];
  const int tid = threadIdx.x;
  const size_t tile = blockIdx.x;            // 0..2047
  const float4* ks = (const float4*)(x2 + tile * 4096);
  const float4* vs = (const float4*)(x1 + tile * 4096);
#pragma unroll
  for (int it = 0; it < 4; ++it) {
    int f = it * 256 + tid;
    int row = f >> 5, c4 = f & 31;
    float4 kv = ks[f];
    float4 vv = vs[f];
    *(uint2*)&Kl[row * 136 + c4 * 4] = uint2{pk2rn(kv.x, kv.y), pk2rn(kv.z, kv.w)};
    *(uint2*)&Vl[row * 136 + c4 * 4] = uint2{pk2rn(vv.x, vv.y), pk2rn(vv.z, vv.w)};
  }
  __syncthreads();
#pragma unroll
  for (int it = 0; it < 2; ++it) {
    int u = it * 256 + tid;
    int lane = u & 63, grp = u >> 6;
    int mt = grp >> 2, c = grp & 3, m16 = lane & 15, g = lane >> 4;
    uint4 w = *(const uint4*)&Kl[(mt * 16 + m16) * 136 + c * 32 + g * 8];
    Kb[tile * 512 + u] = w;
  }
#pragma unroll
  for (int it = 0; it < 2; ++it) {
    int u = it * 256 + tid;
    int lane = u & 63, dt = u >> 6, m16 = lane & 15, g = lane >> 4;
    int d = dt * 16 + m16, k0 = g * 8;
    unsigned w[4];
#pragma unroll
    for (int p = 0; p < 4; ++p) {
      unsigned lo = Vl[(k0 + 2 * p) * 136 + d];
      unsigned hi = Vl[(k0 + 2 * p + 1) * 136 + d];
      w[p] = lo | (hi << 16);
    }
    Vt[tile * 512 + u] = uint4{w[0], w[1], w[2], w[3]};
  }
}

// ---------------- main kernel ----------------------------------------------
__global__ __launch_bounds__(256, 4)
void attn5(const uint4* __restrict__ Kb, const uint4* __restrict__ Vt,
           const float* __restrict__ x1, const float* __restrict__ x2,
           const float* __restrict__ x3, float* __restrict__ out) {
  __shared__ uint4 smemv[(PS_OFF + 5120) / 16];   // 37888 B total
  char* smem = (char*)smemv;
  float* Os = (float*)smem;                       // epilogue overlay

  const int tid = threadIdx.x, wave = tid >> 6, lane = tid & 63;
  const int g = lane >> 4, q = lane & 15;
  const int blk = blockIdx.x, bh = blk & 31, qt = blk >> 5;

  const float* X1 = x1 + (size_t)bh * (Sc * Dc);
  const float* X2 = x2 + (size_t)bh * (Sc * Dc);
  float* outp = out + (size_t)bh * (Sc * Dc);
  const float cl2 = (1.0f / x3[bh]) * 1.4426950408889634f;  // fold log2(e)

  const int qrow = qt * 64 + wave * 16 + q;
  const unsigned row_base = (unsigned)(bh * Sc + qrow) * (unsigned)Sc;

  // Q B-frags: qf[c] = Q[qrow][c*32 + g*8 .. +7]
  bf16x8 qf[4];
  {
    const float4* qsrc = (const float4*)(X1 + (size_t)qrow * Dc);
#pragma unroll
    for (int c = 0; c < 4; ++c) {
      float4 f0 = qsrc[c * 8 + g * 2], f1 = qsrc[c * 8 + g * 2 + 1];
      U8 cv; cv.u = uint4{pk2rn(f0.x, f0.y), pk2rn(f0.z, f0.w),
                          pk2rn(f1.x, f1.y), pk2rn(f1.z, f1.w)};
      qf[c] = cv.v;
    }
  }

  f32x4 o[8];
#pragma unroll
  for (int i = 0; i < 8; ++i) o[i] = f32x4{0.f, 0.f, 0.f, 0.f};
  float l_run = 0.0f;
  const size_t tgbase = (size_t)bh * 64;
  char* pwb = smem + PS_OFF + wave * 1280 + q * PS_STRIDE;  // this lane's P row

  // prologue: stage tile 0 into buffer 0
  {
    const char* kg = (const char*)(Kb + tgbase * 512);
    const char* vg = (const char*)(Vt + tgbase * 512);
#pragma unroll
    for (int j = 0; j < 2; ++j) {
      int off = j * 4096 + tid * 16;
      gload16(kg + off, smem + off);
      gload16(vg + off, smem + TILE_B + off);
    }
  }

  for (int t = 0; t < NT; ++t) {
    const int b = t & 1;
    char* cur = smem + b * (2 * TILE_B);
    char* nxt = smem + (b ^ 1) * (2 * TILE_B);
    __builtin_amdgcn_s_waitcnt(0x0F70);   // vmcnt(0): tile-t DMA landed
    __syncthreads();                      // + prev readers of nxt done
    if (t + 1 < NT) {                     // prefetch tile t+1 (rides compute)
      const char* kg = (const char*)(Kb + (tgbase + t + 1) * 512);
      const char* vg = (const char*)(Vt + (tgbase + t + 1) * 512);
#pragma unroll
      for (int j = 0; j < 2; ++j) {
        int off = j * 4096 + tid * 16;
        gload16(kg + off, nxt + off);
        gload16(vg + off, nxt + TILE_B + off);
      }
    }

    // ---- S^T = K·Q^T : C col = q, row(key in mt-group) = g*4 + reg ----
    f32x4 s0 = {}, s1 = {};
#pragma unroll
    for (int c = 0; c < 4; ++c) {
      U8 a0; a0.u = *(const uint4*)(cur + ((0 * 4 + c) * 64 + lane) * 16);
      U8 a1; a1.u = *(const uint4*)(cur + ((1 * 4 + c) * 64 + lane) * 16);
      s0 = __builtin_amdgcn_mfma_f32_16x16x32_bf16(a0.v, qf[c], s0, 0, 0, 0);
      s1 = __builtin_amdgcn_mfma_f32_16x16x32_bf16(a1.v, qf[c], s1, 0, 0, 0);
    }

    // ---- no-max softmax: p = 2^(s*cl2); l excludes dropout ----
    float pr[8];
    float ls = 0.0f;
#pragma unroll
    for (int i = 0; i < 4; ++i) { pr[i]     = __builtin_amdgcn_exp2f(s0[i] * cl2); ls += pr[i]; }
#pragma unroll
    for (int i = 0; i < 4; ++i) { pr[4 + i] = __builtin_amdgcn_exp2f(s1[i] * cl2); ls += pr[4 + i]; }
    ls += __shfl_xor(ls, 16);
    ls += __shfl_xor(ls, 32);
    l_run += ls;

    // ---- threefry keep-masks (8 evals, keys: mt*16 + g*4 + i) ----
    const unsigned ib = row_base + (unsigned)(t * 32) + (unsigned)(g * 4);
    unsigned k00 = keepmask(ib + 0),  k01 = keepmask(ib + 1);
    unsigned k02 = keepmask(ib + 2),  k03 = keepmask(ib + 3);
    unsigned k10 = keepmask(ib + 16), k11 = keepmask(ib + 17);
    unsigned k12 = keepmask(ib + 18), k13 = keepmask(ib + 19);

    // ---- pack + mask + write P (b64, 16 rows x 80B, ~conflict-free) ----
    {
      uint2 w0{pk2rn(pr[0], pr[1]) & hw2(k00, k01),
               pk2rn(pr[2], pr[3]) & hw2(k02, k03)};
      uint2 w1{pk2rn(pr[4], pr[5]) & hw2(k10, k11),
               pk2rn(pr[6], pr[7]) & hw2(k12, k13)};
      *(uint2*)(pwb + 0 * 32 + g * 8) = w0;
      *(uint2*)(pwb + 1 * 32 + g * 8) = w1;
    }

    // ---- O^T += V^T·P^T (B-frag = one b128 from own wave's P rows) ----
    U8 bfr; bfr.u = *(const uint4*)(smem + PS_OFF + wave * 1280 + q * PS_STRIDE + g * 16);
#pragma unroll
    for (int dt = 0; dt < 8; ++dt) {
      U8 av; av.u = *(const uint4*)(cur + TILE_B + (dt * 64 + lane) * 16);
      o[dt] = __builtin_amdgcn_mfma_f32_16x16x32_bf16(av.v, bfr.v, o[dt], 0, 0, 0);
    }
  }

  // ---- epilogue: O^T (col=q, row=d) -> LDS transpose -> +x2 residual ----
  const float invl = 2.0f / l_run;   // 1/(1-p) / l
  __builtin_amdgcn_s_waitcnt(0x0F70);
  __syncthreads();
  {
    float* ow = Os + (size_t)(wave * 16 + q) * 132;
#pragma unroll
    for (int dt = 0; dt < 8; ++dt) {
      int d = dt * 16 + g * 4;
      *(float4*)&ow[d] = float4{o[dt][0] * invl, o[dt][1] * invl,
                                o[dt][2] * invl, o[dt][3] * invl};
    }
  }
  __syncthreads();
#pragma unroll
  for (int it = 0; it < 8; ++it) {
    int f = it * 256 + tid;
    int ql = f >> 5, c4 = f & 31;
    float4 ov = *(const float4*)&Os[ql * 132 + c4 * 4];
    size_t goff = (size_t)(qt * 64 + ql) * Dc + c4 * 4;
    float4 xv = *(const float4*)&X2[goff];
    *(float4*)&outp[goff] = float4{ov.x + xv.x, ov.y + xv.y, ov.z + xv.z, ov.w + xv.w};
  }
}

extern "C" void kernel_launch(void* const* d_in, const int* in_sizes, int n_in,
                              void* d_out, int out_size, void* d_ws, size_t ws_size,
                              hipStream_t stream) {
  const float* x1 = (const float*)d_in[0];
  const float* x2 = (const float*)d_in[1];
  const float* x3 = (const float*)d_in[2];
  float* out = (float*)d_out;
  const size_t PREP = (size_t)2048 * 512 * 16;   // 16.78 MB per bf16 image
  uint4* Kb = (uint4*)d_ws;
  uint4* Vtg = (uint4*)((char*)d_ws + PREP);
  prepack<<<2048, 256, 0, stream>>>(x1, x2, Kb, Vtg);
  attn5<<<1024, 256, 0, stream>>>(Kb, Vtg, x1, x2, x3, out);
}

// Round 6
// 405.287 us; speedup vs baseline: 1.1968x; 1.1968x over previous
//
#include <hip/hip_runtime.h>
#include <math.h>

// Model_39676907887961: out = dropout(softmax(x1@x2^T / x3)) @ x1 + x2
// B=2 H=16 S=2048 D=128. Round 6: r4 BK=64 single-buffer structure +
// (1) v_alignbit rotates in threefry, (2) threefry moved between DMA issue
// and barrier (hides staging latency without dbuf), (3) perm/and mask apply,
// same-wave P exchange (no extra barrier). LDS 40960 -> 4 blocks/CU.
// Threefry2x32 key(42) partitionable (r1); no-max softmax (r3).

constexpr int Sc = 2048, Dc = 128;
constexpr int NT = 32;                     // 32 tiles of BK=64 (2x 32-key images)
constexpr int VOFF = 16384;                // V region in LDS
constexpr int POFF = 32768;                // P region: 4 waves x 16 rows x 128 B

typedef short bf16x8 __attribute__((ext_vector_type(8)));
typedef float f32x4 __attribute__((ext_vector_type(4)));
union U8 { uint4 u; bf16x8 v; };

__device__ __forceinline__ unsigned rotl(unsigned x, int r) {
  return __builtin_amdgcn_alignbit(x, x, 32 - r);   // rotl(x,r) = rotr(x,32-r)
}

// JAX Threefry-2x32, 20 rounds, key = (0, 42) — verified partitionable path
__device__ __forceinline__ void tf2x32(unsigned x0, unsigned x1,
                                       unsigned &o0, unsigned &o1) {
  const unsigned ks0 = 0u, ks1 = 42u;
  const unsigned ks2 = 0x1BD11BDAu ^ 0u ^ 42u;
  x0 += ks0; x1 += ks1;
#define TFR(r) { x0 += x1; x1 = rotl(x1, r); x1 ^= x0; }
  TFR(13) TFR(15) TFR(26) TFR(6)
  x0 += ks1; x1 += ks2 + 1u;
  TFR(17) TFR(29) TFR(16) TFR(24)
  x0 += ks2; x1 += ks0 + 2u;
  TFR(13) TFR(15) TFR(26) TFR(6)
  x0 += ks0; x1 += ks1 + 3u;
  TFR(17) TFR(29) TFR(16) TFR(24)
  x0 += ks1; x1 += ks2 + 4u;
  TFR(13) TFR(15) TFR(26) TFR(6)
  x0 += ks2; x1 += ks0 + 5u;
#undef TFR
  o0 = x0; o1 = x1;
}

// keep-mask: 0xFFFFFFFF iff MSB(o0^o1)==0 (uniform<0.5 => keep)
__device__ __forceinline__ unsigned keepmask(unsigned idx) {
  unsigned a, b; tf2x32(0u, idx, a, b);
  return (unsigned)(((int)~(a ^ b)) >> 31);
}

// pack two f32 -> bf16 pair (round-half-up via +0x8000, then v_perm)
__device__ __forceinline__ unsigned pk2rn(float a, float b) {
  return __builtin_amdgcn_perm(__float_as_uint(b) + 0x8000u,
                               __float_as_uint(a) + 0x8000u, 0x07060302u);
}

// halfword-combine two full-width masks: lo16 from ma, hi16 from mb
__device__ __forceinline__ unsigned hw2(unsigned ma, unsigned mb) {
  return __builtin_amdgcn_perm(mb, ma, 0x05040100u);
}

__device__ __forceinline__ void gload16(const void* g, void* l) {
  __builtin_amdgcn_global_load_lds(
      (const __attribute__((address_space(1))) void*)g,
      (__attribute__((address_space(3))) void*)l, 16, 0, 0);
}

// ---------------- pre-pass (r5, proven): fragment-linear bf16 images --------
// Per 32-key tile (tile index = bh*64 + tt):
//  K unit u = (mt*4+c)*64 + lane : K[mt*16+(lane&15)][c*32+(lane>>4)*8 .. +7]
//  V unit u = dt*64 + lane       : V[(lane>>4)*8+2p(+1)][dt*16+(lane&15)] pairs
__global__ __launch_bounds__(256)
void prepack(const float* __restrict__ x1, const float* __restrict__ x2,
             uint4* __restrict__ Kb, uint4* __restrict__ Vt) {
  __shared__ ushort Kl[32 * 136];
  __shared__ ushort Vl[32 * 136];
  const int tid = threadIdx.x;
  const size_t tile = blockIdx.x;            // 0..2047
  const float4* ks = (const float4*)(x2 + tile * 4096);
  const float4* vs = (const float4*)(x1 + tile * 4096);
#pragma unroll
  for (int it = 0; it < 4; ++it) {
    int f = it * 256 + tid;
    int row = f >> 5, c4 = f & 31;
    float4 kv = ks[f];
    float4 vv = vs[f];
    *(uint2*)&Kl[row * 136 + c4 * 4] = uint2{pk2rn(kv.x, kv.y), pk2rn(kv.z, kv.w)};
    *(uint2*)&Vl[row * 136 + c4 * 4] = uint2{pk2rn(vv.x, vv.y), pk2rn(vv.z, vv.w)};
  }
  __syncthreads();
#pragma unroll
  for (int it = 0; it < 2; ++it) {
    int u = it * 256 + tid;
    int lane = u & 63, grp = u >> 6;
    int mt = grp >> 2, c = grp & 3, m16 = lane & 15, g = lane >> 4;
    Kb[tile * 512 + u] = *(const uint4*)&Kl[(mt * 16 + m16) * 136 + c * 32 + g * 8];
  }
#pragma unroll
  for (int it = 0; it < 2; ++it) {
    int u = it * 256 + tid;
    int lane = u & 63, dt = u >> 6, m16 = lane & 15, g = lane >> 4;
    int d = dt * 16 + m16, k0 = g * 8;
    unsigned w[4];
#pragma unroll
    for (int p = 0; p < 4; ++p) {
      unsigned lo = Vl[(k0 + 2 * p) * 136 + d];
      unsigned hi = Vl[(k0 + 2 * p + 1) * 136 + d];
      w[p] = lo | (hi << 16);
    }
    Vt[tile * 512 + u] = uint4{w[0], w[1], w[2], w[3]};
  }
}

// ---------------- main kernel ----------------------------------------------
__global__ __launch_bounds__(256, 4)
void attn6(const uint4* __restrict__ Kb, const uint4* __restrict__ Vt,
           const float* __restrict__ x1, const float* __restrict__ x2,
           const float* __restrict__ x3, float* __restrict__ out) {
  __shared__ uint4 smemv[40960 / 16];
  char* smem = (char*)smemv;
  float* Os = (float*)smem;                  // epilogue overlay

  const int tid = threadIdx.x, wave = tid >> 6, lane = tid & 63;
  const int g = lane >> 4, q = lane & 15;
  const int blk = blockIdx.x, bh = blk & 31, qt = blk >> 5;

  const float* X1 = x1 + (size_t)bh * (Sc * Dc);
  const float* X2 = x2 + (size_t)bh * (Sc * Dc);
  float* outp = out + (size_t)bh * (Sc * Dc);
  const float cl2 = (1.0f / x3[bh]) * 1.4426950408889634f;   // fold log2(e)

  const int qrow = qt * 64 + wave * 16 + q;
  const unsigned row_base = (unsigned)(bh * Sc + qrow) * (unsigned)Sc;
  char* prow = smem + POFF + wave * 2048 + q * 128;   // this lane's P row

  // Q B-frags: qf[c] = Q[qrow][c*32 + g*8 .. +7]
  bf16x8 qf[4];
  {
    const float4* qsrc = (const float4*)(X1 + (size_t)qrow * Dc);
#pragma unroll
    for (int c = 0; c < 4; ++c) {
      float4 f0 = qsrc[c * 8 + g * 2], f1 = qsrc[c * 8 + g * 2 + 1];
      U8 cv; cv.u = uint4{pk2rn(f0.x, f0.y), pk2rn(f0.z, f0.w),
                          pk2rn(f1.x, f1.y), pk2rn(f1.z, f1.w)};
      qf[c] = cv.v;
    }
  }

  f32x4 o[8];
#pragma unroll
  for (int i = 0; i < 8; ++i) o[i] = f32x4{0.f, 0.f, 0.f, 0.f};
  float l_run = 0.0f;
  const size_t tg = (size_t)bh * 64;

  for (int t = 0; t < NT; ++t) {
    __syncthreads();                 // barrier-A: prior tile's readers done
    // ---- issue DMA for tile t (two 32-key subtiles for K and for V) ----
    {
      const char* kg = (const char*)(Kb + (tg + 2 * t) * 512);
      const char* vg = (const char*)(Vt + (tg + 2 * t) * 512);
      const int off = wave * 1024 + lane * 16;
#pragma unroll
      for (int h = 0; h < 2; ++h) {
        gload16(kg + h * 8192 + off,        smem + h * 8192 + off);
        gload16(kg + h * 8192 + off + 4096, smem + h * 8192 + off + 4096);
        gload16(vg + h * 8192 + off,        smem + VOFF + h * 8192 + off);
        gload16(vg + h * 8192 + off + 4096, smem + VOFF + h * 8192 + off + 4096);
      }
    }
    __builtin_amdgcn_sched_barrier(0);   // keep DMA issue ahead of threefry

    // ---- threefry keep-masks for this tile (data-independent: hides DMA) --
    // key for (h2 = h*2+m, i): h2*16 + g*4 + i
    unsigned km[8];
    {
      const unsigned ib = row_base + (unsigned)(t * 64) + (unsigned)(g * 4);
#pragma unroll
      for (int h2 = 0; h2 < 4; ++h2) {
        unsigned a0 = keepmask(ib + h2 * 16 + 0), a1 = keepmask(ib + h2 * 16 + 1);
        unsigned a2 = keepmask(ib + h2 * 16 + 2), a3 = keepmask(ib + h2 * 16 + 3);
        km[h2 * 2 + 0] = hw2(a0, a1);
        km[h2 * 2 + 1] = hw2(a2, a3);
      }
    }
    __syncthreads();                 // barrier-B (implicit vmcnt(0): DMA done)

    // ---- S^T = K·Q^T : s[h2][reg] = score(key = h2*16 + g*4 + reg, col q) --
    f32x4 s0 = {}, s1 = {}, s2 = {}, s3 = {};
#pragma unroll
    for (int c = 0; c < 4; ++c) {
      U8 a0; a0.u = *(const uint4*)(smem +        ((0 * 4 + c) * 64 + lane) * 16);
      U8 a1; a1.u = *(const uint4*)(smem +        ((1 * 4 + c) * 64 + lane) * 16);
      U8 a2; a2.u = *(const uint4*)(smem + 8192 + ((0 * 4 + c) * 64 + lane) * 16);
      U8 a3; a3.u = *(const uint4*)(smem + 8192 + ((1 * 4 + c) * 64 + lane) * 16);
      s0 = __builtin_amdgcn_mfma_f32_16x16x32_bf16(a0.v, qf[c], s0, 0, 0, 0);
      s1 = __builtin_amdgcn_mfma_f32_16x16x32_bf16(a1.v, qf[c], s1, 0, 0, 0);
      s2 = __builtin_amdgcn_mfma_f32_16x16x32_bf16(a2.v, qf[c], s2, 0, 0, 0);
      s3 = __builtin_amdgcn_mfma_f32_16x16x32_bf16(a3.v, qf[c], s3, 0, 0, 0);
    }

    // ---- no-max softmax: p = 2^(s*cl2); l excludes dropout ----
    float pr[16];
    float ls = 0.0f;
#pragma unroll
    for (int i = 0; i < 4; ++i) { pr[i]      = __builtin_amdgcn_exp2f(s0[i] * cl2); ls += pr[i]; }
#pragma unroll
    for (int i = 0; i < 4; ++i) { pr[4 + i]  = __builtin_amdgcn_exp2f(s1[i] * cl2); ls += pr[4 + i]; }
#pragma unroll
    for (int i = 0; i < 4; ++i) { pr[8 + i]  = __builtin_amdgcn_exp2f(s2[i] * cl2); ls += pr[8 + i]; }
#pragma unroll
    for (int i = 0; i < 4; ++i) { pr[12 + i] = __builtin_amdgcn_exp2f(s3[i] * cl2); ls += pr[12 + i]; }
    ls += __shfl_xor(ls, 16);
    ls += __shfl_xor(ls, 32);
    l_run += ls;

    // ---- pack + mask + write P units (unit u = h2*4... u = (h2>>1)*8+(h2&1)*4+g,
    //      4 bf16 keys each; XOR-swizzled by q, same-wave exchange, no barrier)
#pragma unroll
    for (int h2 = 0; h2 < 4; ++h2) {
      unsigned w0 = pk2rn(pr[h2 * 4 + 0], pr[h2 * 4 + 1]) & km[h2 * 2 + 0];
      unsigned w1 = pk2rn(pr[h2 * 4 + 2], pr[h2 * 4 + 3]) & km[h2 * 2 + 1];
      int u = (h2 >> 1) * 8 + (h2 & 1) * 4 + g;
      *(uint2*)(prow + ((u ^ q) & 15) * 8) = uint2{w0, w1};
    }

    // ---- B-frags for PV from P rows (b64 pairs, swizzle-aware order) ----
    U8 bf0, bf1;
    {
      int u0 = 2 * g;            // kh = 0: keys g*8 .. +7
      uint2 lo0 = *(const uint2*)(prow + (((u0 + 0) ^ q) & 15) * 8);
      uint2 hi0 = *(const uint2*)(prow + (((u0 + 1) ^ q) & 15) * 8);
      bf0.u = uint4{lo0.x, lo0.y, hi0.x, hi0.y};
      int u1 = 8 + 2 * g;        // kh = 1: keys 32 + g*8 .. +7
      uint2 lo1 = *(const uint2*)(prow + (((u1 + 0) ^ q) & 15) * 8);
      uint2 hi1 = *(const uint2*)(prow + (((u1 + 1) ^ q) & 15) * 8);
      bf1.u = uint4{lo1.x, lo1.y, hi1.x, hi1.y};
    }

    // ---- O^T += V^T·P^T (two k-halves per d-tile) ----
#pragma unroll
    for (int dt = 0; dt < 8; ++dt) {
      U8 av0; av0.u = *(const uint4*)(smem + VOFF +        (dt * 64 + lane) * 16);
      U8 av1; av1.u = *(const uint4*)(smem + VOFF + 8192 + (dt * 64 + lane) * 16);
      o[dt] = __builtin_amdgcn_mfma_f32_16x16x32_bf16(av0.v, bf0.v, o[dt], 0, 0, 0);
      o[dt] = __builtin_amdgcn_mfma_f32_16x16x32_bf16(av1.v, bf1.v, o[dt], 0, 0, 0);
    }
  }

  // ---- epilogue: O^T (col=q, row=d) -> LDS transpose -> +x2 residual ----
  const float invl = 2.0f / l_run;   // 1/(1-p) / l
  __syncthreads();
  {
    float* ow = Os + (size_t)(wave * 16 + q) * 132;
#pragma unroll
    for (int dt = 0; dt < 8; ++dt) {
      int d = dt * 16 + g * 4;
      *(float4*)&ow[d] = float4{o[dt][0] * invl, o[dt][1] * invl,
                                o[dt][2] * invl, o[dt][3] * invl};
    }
  }
  __syncthreads();
#pragma unroll
  for (int it = 0; it < 8; ++it) {
    int f = it * 256 + tid;
    int ql = f >> 5, c4 = f & 31;
    float4 ov = *(const float4*)&Os[ql * 132 + c4 * 4];
    size_t goff = (size_t)(qt * 64 + ql) * Dc + c4 * 4;
    float4 xv = *(const float4*)&X2[goff];
    *(float4*)&outp[goff] = float4{ov.x + xv.x, ov.y + xv.y, ov.z + xv.z, ov.w + xv.w};
  }
}

extern "C" void kernel_launch(void* const* d_in, const int* in_sizes, int n_in,
                              void* d_out, int out_size, void* d_ws, size_t ws_size,
                              hipStream_t stream) {
  const float* x1 = (const float*)d_in[0];
  const float* x2 = (const float*)d_in[1];
  const float* x3 = (const float*)d_in[2];
  float* out = (float*)d_out;
  const size_t PREP = (size_t)2048 * 512 * 16;   // 16.78 MB per bf16 image
  uint4* Kb = (uint4*)d_ws;
  uint4* Vtg = (uint4*)((char*)d_ws + PREP);
  prepack<<<2048, 256, 0, stream>>>(x1, x2, Kb, Vtg);
  attn6<<<1024, 256, 0, stream>>>(Kb, Vtg, x1, x2, x3, out);
}